// Round 1
// baseline (703.673 us; speedup 1.0000x reference)
//
#include <hip/hip_runtime.h>
#include <hip/hip_bf16.h>
#include <math.h>

#define Bc 4
#define Sc 2048
#define Dc 1024
#define Hc 16
#define DKc 64
#define DFFc 4096
#define Mc (Bc*Sc)
#define LN_EPS 1e-6f

typedef unsigned short ushort_t;
typedef short bf16x8 __attribute__((ext_vector_type(8)));
typedef float f32x4 __attribute__((ext_vector_type(4)));

typedef __attribute__((address_space(3))) void lds_void_t;
typedef __attribute__((address_space(1))) const void gconst_void_t;

__device__ __forceinline__ void gload_lds16(const void* g, void* l) {
  __builtin_amdgcn_global_load_lds((gconst_void_t*)g, (lds_void_t*)l, 16, 0, 0);
}

__device__ __forceinline__ ushort_t f2bf(float f) {
  union { float f; unsigned int u; } a; a.f = f;
  unsigned int r = a.u + 0x7fffu + ((a.u >> 16) & 1u);
  return (ushort_t)(r >> 16);
}

// ---------------- weight transpose + f32->bf16 convert ----------------
// W: [K,N] f32 row-major  ->  WT: [N,K] bf16 row-major
__global__ __launch_bounds__(256) void k_transpose_cvt(
    const float* __restrict__ W, ushort_t* __restrict__ WT, int K, int N) {
  __shared__ float t[32][33];
  const int tx = threadIdx.x & 31, ty = threadIdx.x >> 5;  // ty 0..7
  const int n0 = blockIdx.x * 32, k0 = blockIdx.y * 32;
#pragma unroll
  for (int i = 0; i < 4; ++i)
    t[ty + i * 8][tx] = W[(size_t)(k0 + ty + i * 8) * N + n0 + tx];
  __syncthreads();
#pragma unroll
  for (int i = 0; i < 4; ++i)
    WT[(size_t)(n0 + ty + i * 8) * K + k0 + tx] = f2bf(t[tx][ty + i * 8]);
}

// ---------------- layernorm (f32 in -> bf16 out), ddof=1, /(std+eps) ----------------
__global__ __launch_bounds__(256) void k_layernorm(
    const float* __restrict__ x, const float* __restrict__ alpha,
    const float* __restrict__ beta, ushort_t* __restrict__ out) {
  const int row = blockIdx.x;
  const int tid = threadIdx.x;
  const int w = tid >> 6, lane = tid & 63;
  const float4 v = ((const float4*)(x + (size_t)row * Dc))[tid];
  float s = v.x + v.y + v.z + v.w;
#pragma unroll
  for (int m = 32; m >= 1; m >>= 1) s += __shfl_xor(s, m, 64);
  __shared__ float ws[8];
  if (lane == 0) ws[w] = s;
  __syncthreads();
  s = ws[0] + ws[1] + ws[2] + ws[3];
  const float mean = s * (1.0f / Dc);
  const float dx = v.x - mean, dy = v.y - mean, dz = v.z - mean, dw = v.w - mean;
  float ss = dx * dx + dy * dy + dz * dz + dw * dw;
#pragma unroll
  for (int m = 32; m >= 1; m >>= 1) ss += __shfl_xor(ss, m, 64);
  if (lane == 0) ws[4 + w] = ss;
  __syncthreads();
  ss = ws[4] + ws[5] + ws[6] + ws[7];
  const float stdv = sqrtf(ss / (float)(Dc - 1));
  const float inv = 1.0f / (stdv + LN_EPS);
  const float4 a = ((const float4*)alpha)[tid];
  const float4 b = ((const float4*)beta)[tid];
  ushort4 o;
  o.x = f2bf(a.x * dx * inv + b.x);
  o.y = f2bf(a.y * dy * inv + b.y);
  o.z = f2bf(a.z * dz * inv + b.z);
  o.w = f2bf(a.w * dw * inv + b.w);
  *(ushort4*)(out + (size_t)row * Dc + tid * 4) = o;
}

// ---------------- bf16 GEMM, m97 structure: 128x128 tile, BK=32, 4 waves ----------------
// A: [M,K] bf16 row-major.  BT: [N,K] bf16 row-major.  C = A*B + bias (+resid)
// MODE 0: bf16 out.  MODE 1: f32 out with +resid.  MODE 2: gelu -> bf16 out.
template <int MODE>
__global__ __launch_bounds__(256) void k_gemm(
    const ushort_t* __restrict__ A, const ushort_t* __restrict__ BT,
    const float* __restrict__ bias, const float* __restrict__ resid,
    void* __restrict__ Cout, int N, int K) {
  __shared__ __align__(16) ushort_t As[128 * 32];
  __shared__ __align__(16) ushort_t Bs[128 * 32];
  const int tid = threadIdx.x;
  const int lane = tid & 63;
  const int w = tid >> 6, wm = w >> 1, wn = w & 1;
  const int lrow = lane & 15, lgrp = lane >> 4;
  const int m0 = blockIdx.y << 7, n0 = blockIdx.x << 7;

  const f32x4 zero4 = {0.f, 0.f, 0.f, 0.f};
  f32x4 acc[4][4];
#pragma unroll
  for (int i = 0; i < 4; ++i)
#pragma unroll
    for (int j = 0; j < 4; ++j) acc[i][j] = zero4;

  const int c0 = tid, c1 = tid + 256;  // 16B chunks, 512 per 128x32 tile
  const ushort_t* Ag0 = A + (size_t)(m0 + (c0 >> 2)) * K + (c0 & 3) * 8;
  const ushort_t* Ag1 = A + (size_t)(m0 + (c1 >> 2)) * K + (c1 & 3) * 8;
  const ushort_t* Bg0 = BT + (size_t)(n0 + (c0 >> 2)) * K + (c0 & 3) * 8;
  const ushort_t* Bg1 = BT + (size_t)(n0 + (c1 >> 2)) * K + (c1 & 3) * 8;
  ushort_t* Al0 = As + c0 * 8;
  ushort_t* Al1 = As + c1 * 8;
  ushort_t* Bl0 = Bs + c0 * 8;
  ushort_t* Bl1 = Bs + c1 * 8;

  int aoff[4], boff[4];
#pragma unroll
  for (int m = 0; m < 4; ++m) aoff[m] = (wm * 64 + m * 16 + lrow) * 32 + lgrp * 8;
#pragma unroll
  for (int n = 0; n < 4; ++n) boff[n] = (wn * 64 + n * 16 + lrow) * 32 + lgrp * 8;

  for (int kk = 0; kk < K; kk += 32) {
    gload_lds16(Ag0 + kk, Al0);
    gload_lds16(Ag1 + kk, Al1);
    gload_lds16(Bg0 + kk, Bl0);
    gload_lds16(Bg1 + kk, Bl1);
    __syncthreads();  // drains vmcnt -> tile resident
    bf16x8 a[4], b[4];
#pragma unroll
    for (int m = 0; m < 4; ++m) a[m] = *(const bf16x8*)(As + aoff[m]);
#pragma unroll
    for (int n = 0; n < 4; ++n) b[n] = *(const bf16x8*)(Bs + boff[n]);
#pragma unroll
    for (int m = 0; m < 4; ++m)
#pragma unroll
      for (int n = 0; n < 4; ++n)
        acc[m][n] = __builtin_amdgcn_mfma_f32_16x16x32_bf16(a[m], b[n], acc[m][n], 0, 0, 0);
    __syncthreads();  // readers done before next stage overwrites
  }

  float bv[4];
#pragma unroll
  for (int n = 0; n < 4; ++n) bv[n] = bias[n0 + wn * 64 + n * 16 + lrow];
#pragma unroll
  for (int m = 0; m < 4; ++m)
#pragma unroll
    for (int n = 0; n < 4; ++n)
#pragma unroll
      for (int r = 0; r < 4; ++r) {
        const size_t row = (size_t)(m0 + wm * 64 + m * 16 + lgrp * 4 + r);
        const size_t col = (size_t)(n0 + wn * 64 + n * 16 + lrow);
        float v = acc[m][n][r] + bv[n];
        if (MODE == 2) v = 0.5f * v * (1.0f + erff(v * 0.70710678118654752f));
        if (MODE == 1) {
          v += resid[row * N + col];
          ((float*)Cout)[row * N + col] = v;
        } else {
          ((ushort_t*)Cout)[row * N + col] = f2bf(v);
        }
      }
}

// ---------------- flash attention: 64 q-rows/block, 4 waves x 16 rows ----------------
// Q,K,V: [B,S,H*DK] bf16.  O: [B,S,H*DK] bf16.  mask: [B,S] int (0 => -1e9)
__global__ __launch_bounds__(256) void k_attn(
    const ushort_t* __restrict__ Qb, const ushort_t* __restrict__ Kb,
    const ushort_t* __restrict__ Vb, const int* __restrict__ mask,
    ushort_t* __restrict__ Ob) {
  const int bh = blockIdx.y;
  const int b = bh >> 4, h = bh & 15;
  const int qb = blockIdx.x * 64;
  const int tid = threadIdx.x;
  const int lane = tid & 63, w = tid >> 6;
  const int lrow = lane & 15, lgrp = lane >> 4;
  const size_t bS = (size_t)b * Sc;

  __shared__ __align__(16) ushort_t VT[64][72];      // V^T tile, +8 pad: 2-way-free reads
  __shared__ __align__(16) ushort_t Pl[4][16][72];   // per-wave P tile

  const f32x4 zero4 = {0.f, 0.f, 0.f, 0.f};
  // Q fragments (A-operand): row = lrow, k = lgrp*8+j
  const ushort_t* qp = Qb + (bS + qb + w * 16 + lrow) * Dc + h * DKc;
  const bf16x8 qf0 = *(const bf16x8*)(qp + lgrp * 8);
  const bf16x8 qf1 = *(const bf16x8*)(qp + 32 + lgrp * 8);

  f32x4 acc[4];
#pragma unroll
  for (int n = 0; n < 4; ++n) acc[n] = zero4;
  float rowm[4], rowl[4];
#pragma unroll
  for (int r = 0; r < 4; ++r) { rowm[r] = -INFINITY; rowl[r] = 0.f; }

  for (int kv = 0; kv < Sc; kv += 64) {
    __syncthreads();  // previous PV readers done; safe to overwrite VT
    // stage V^T (transposing reg->LDS)
#pragma unroll
    for (int u = 0; u < 2; ++u) {
      const int c = tid + u * 256;       // 512 chunks of 8 bf16
      const int sk = c >> 3, d8 = c & 7;
      const bf16x8 vv = *(const bf16x8*)(Vb + (bS + kv + sk) * Dc + h * DKc + d8 * 8);
#pragma unroll
      for (int j = 0; j < 8; ++j) VT[d8 * 8 + j][sk] = (ushort_t)vv[j];
    }
    // masks for the 4 sk sub-tiles this lane's column touches
    int mv[4];
#pragma unroll
    for (int n = 0; n < 4; ++n) mv[n] = mask[bS + kv + n * 16 + lrow];
    // QK^T: S-tile [16q][64sk], B-operand fragments straight from global K rows
    f32x4 sc[4];
#pragma unroll
    for (int n = 0; n < 4; ++n) sc[n] = zero4;
#pragma unroll
    for (int n = 0; n < 4; ++n) {
      const ushort_t* kp = Kb + (bS + kv + n * 16 + lrow) * Dc + h * DKc;
      const bf16x8 kf0 = *(const bf16x8*)(kp + lgrp * 8);
      const bf16x8 kf1 = *(const bf16x8*)(kp + 32 + lgrp * 8);
      sc[n] = __builtin_amdgcn_mfma_f32_16x16x32_bf16(qf0, kf0, sc[n], 0, 0, 0);
      sc[n] = __builtin_amdgcn_mfma_f32_16x16x32_bf16(qf1, kf1, sc[n], 0, 0, 0);
    }
    // online softmax, wave-parallel (rows live in 16-lane groups)
    float sv[4][4];
#pragma unroll
    for (int n = 0; n < 4; ++n)
#pragma unroll
      for (int r = 0; r < 4; ++r)
        sv[n][r] = (mv[n] != 0) ? sc[n][r] * 0.125f : -1e9f;
    float pm[4];
#pragma unroll
    for (int r = 0; r < 4; ++r) {
      pm[r] = fmaxf(fmaxf(sv[0][r], sv[1][r]), fmaxf(sv[2][r], sv[3][r]));
#pragma unroll
      for (int mm = 8; mm >= 1; mm >>= 1) pm[r] = fmaxf(pm[r], __shfl_xor(pm[r], mm, 16));
    }
    float scl[4];
#pragma unroll
    for (int r = 0; r < 4; ++r) {
      const float mn = fmaxf(rowm[r], pm[r]);
      scl[r] = __expf(rowm[r] - mn);
      rowm[r] = mn;
    }
    float p[4][4], ps[4];
#pragma unroll
    for (int r = 0; r < 4; ++r) ps[r] = 0.f;
#pragma unroll
    for (int n = 0; n < 4; ++n)
#pragma unroll
      for (int r = 0; r < 4; ++r) {
        p[n][r] = __expf(sv[n][r] - rowm[r]);
        ps[r] += p[n][r];
      }
#pragma unroll
    for (int r = 0; r < 4; ++r) {
#pragma unroll
      for (int mm = 8; mm >= 1; mm >>= 1) ps[r] += __shfl_xor(ps[r], mm, 16);
      rowl[r] = rowl[r] * scl[r] + ps[r];
    }
#pragma unroll
    for (int n = 0; n < 4; ++n)
#pragma unroll
      for (int r = 0; r < 4; ++r) acc[n][r] *= scl[r];
    // P (D-layout) -> per-wave LDS so it can be re-read as PV's A-operand
#pragma unroll
    for (int n = 0; n < 4; ++n)
#pragma unroll
      for (int r = 0; r < 4; ++r)
        Pl[w][lgrp * 4 + r][n * 16 + lrow] = f2bf(p[n][r]);
    __syncthreads();  // VT staged by all waves
    // PV: acc += P * V
    const bf16x8 pa0 = *(const bf16x8*)(&Pl[w][lrow][lgrp * 8]);
    const bf16x8 pa1 = *(const bf16x8*)(&Pl[w][lrow][32 + lgrp * 8]);
#pragma unroll
    for (int n2 = 0; n2 < 4; ++n2) {
      const bf16x8 vb0 = *(const bf16x8*)(&VT[n2 * 16 + lrow][lgrp * 8]);
      const bf16x8 vb1 = *(const bf16x8*)(&VT[n2 * 16 + lrow][32 + lgrp * 8]);
      acc[n2] = __builtin_amdgcn_mfma_f32_16x16x32_bf16(pa0, vb0, acc[n2], 0, 0, 0);
      acc[n2] = __builtin_amdgcn_mfma_f32_16x16x32_bf16(pa1, vb1, acc[n2], 0, 0, 0);
    }
  }
  // epilogue
#pragma unroll
  for (int n2 = 0; n2 < 4; ++n2)
#pragma unroll
    for (int r = 0; r < 4; ++r) {
      const int qrow = qb + w * 16 + lgrp * 4 + r;
      const float o = acc[n2][r] / rowl[r];
      Ob[(bS + qrow) * Dc + h * DKc + n2 * 16 + lrow] = f2bf(o);
    }
}

// ---------------- launcher ----------------
extern "C" void kernel_launch(void* const* d_in, const int* in_sizes, int n_in,
                              void* d_out, int out_size, void* d_ws, size_t ws_size,
                              hipStream_t stream) {
  const float* x     = (const float*)d_in[0];
  const int* mask    = (const int*)d_in[1];
  const float* wq_w  = (const float*)d_in[2];
  const float* wq_b  = (const float*)d_in[3];
  const float* wk_w  = (const float*)d_in[4];
  const float* wk_b  = (const float*)d_in[5];
  const float* wv_w  = (const float*)d_in[6];
  const float* wv_b  = (const float*)d_in[7];
  const float* wo_w  = (const float*)d_in[8];
  const float* wo_b  = (const float*)d_in[9];
  const float* ff_w0 = (const float*)d_in[10];
  const float* ff_b0 = (const float*)d_in[11];
  const float* ff_w1 = (const float*)d_in[12];
  const float* ff_b1 = (const float*)d_in[13];
  const float* ln0_a = (const float*)d_in[14];
  const float* ln0_b = (const float*)d_in[15];
  const float* ln1_a = (const float*)d_in[16];
  const float* ln1_b = (const float*)d_in[17];
  float* out = (float*)d_out;

  char* ws = (char*)d_ws;
  size_t off = 0;
  ushort_t* WTq = (ushort_t*)(ws + off); off += (size_t)Dc * Dc * 2;
  ushort_t* WTk = (ushort_t*)(ws + off); off += (size_t)Dc * Dc * 2;
  ushort_t* WTv = (ushort_t*)(ws + off); off += (size_t)Dc * Dc * 2;
  ushort_t* WTo = (ushort_t*)(ws + off); off += (size_t)Dc * Dc * 2;
  ushort_t* WT0 = (ushort_t*)(ws + off); off += (size_t)DFFc * Dc * 2;  // [4096,1024]
  ushort_t* WT1 = (ushort_t*)(ws + off); off += (size_t)Dc * DFFc * 2;  // [1024,4096]
  ushort_t* hbuf = (ushort_t*)(ws + off); off += (size_t)Mc * Dc * 2;
  ushort_t* qbuf = (ushort_t*)(ws + off); off += (size_t)Mc * Dc * 2;
  ushort_t* kbuf = (ushort_t*)(ws + off); off += (size_t)Mc * Dc * 2;
  ushort_t* vbuf = (ushort_t*)(ws + off); off += (size_t)Mc * Dc * 2;
  ushort_t* abuf = (ushort_t*)(ws + off); off += (size_t)Mc * Dc * 2;
  ushort_t* gbuf = qbuf;  // [8192,4096] overlays dead q/k/v/attn buffers (64MB)

  const dim3 blk(256);
  // weight prep
  k_transpose_cvt<<<dim3(Dc / 32, Dc / 32), blk, 0, stream>>>(wq_w, WTq, Dc, Dc);
  k_transpose_cvt<<<dim3(Dc / 32, Dc / 32), blk, 0, stream>>>(wk_w, WTk, Dc, Dc);
  k_transpose_cvt<<<dim3(Dc / 32, Dc / 32), blk, 0, stream>>>(wv_w, WTv, Dc, Dc);
  k_transpose_cvt<<<dim3(Dc / 32, Dc / 32), blk, 0, stream>>>(wo_w, WTo, Dc, Dc);
  k_transpose_cvt<<<dim3(DFFc / 32, Dc / 32), blk, 0, stream>>>(ff_w0, WT0, Dc, DFFc);
  k_transpose_cvt<<<dim3(Dc / 32, DFFc / 32), blk, 0, stream>>>(ff_w1, WT1, DFFc, Dc);
  // LN0
  k_layernorm<<<Mc, blk, 0, stream>>>(x, ln0_a, ln0_b, hbuf);
  // Q,K,V projections
  k_gemm<0><<<dim3(Dc / 128, Mc / 128), blk, 0, stream>>>(hbuf, WTq, wq_b, nullptr, qbuf, Dc, Dc);
  k_gemm<0><<<dim3(Dc / 128, Mc / 128), blk, 0, stream>>>(hbuf, WTk, wk_b, nullptr, kbuf, Dc, Dc);
  k_gemm<0><<<dim3(Dc / 128, Mc / 128), blk, 0, stream>>>(hbuf, WTv, wv_b, nullptr, vbuf, Dc, Dc);
  // attention
  k_attn<<<dim3(Sc / 64, Bc * Hc), blk, 0, stream>>>(qbuf, kbuf, vbuf, mask, abuf);
  // O projection + residual(x) -> d_out (f32)
  k_gemm<1><<<dim3(Dc / 128, Mc / 128), blk, 0, stream>>>(abuf, WTo, wo_b, x, out, Dc, Dc);
  // LN1
  k_layernorm<<<Mc, blk, 0, stream>>>(out, ln1_a, ln1_b, hbuf);
  // FFN0 + exact gelu -> gbuf (bf16)
  k_gemm<2><<<dim3(DFFc / 128, Mc / 128), blk, 0, stream>>>(hbuf, WT0, ff_b0, nullptr, gbuf, DFFc, Dc);
  // FFN1 + residual(d_out) -> d_out (f32), in-place safe (1 thread per element)
  k_gemm<1><<<dim3(Dc / 128, Mc / 128), blk, 0, stream>>>(gbuf, WT1, ff_b1, out, out, Dc, DFFc);
}